// Round 4
// baseline (4582.376 us; speedup 1.0000x reference)
//
#include <hip/hip_runtime.h>
#include <hip/hip_cooperative_groups.h>
#include <hip/hip_bf16.h>

namespace cg = cooperative_groups;

typedef __bf16 bf16;
typedef __bf16 bf16x8 __attribute__((ext_vector_type(8)));
typedef float f32x4 __attribute__((ext_vector_type(4)));

#define MFMA(a, b, c) __builtin_amdgcn_mfma_f32_16x16x32_bf16((a), (b), (c), 0, 0, 0)

// B=32, E=128, T=128, H=512, 4H=2048, E+1=129
// Input float tensors may be device-f32 or device-bf16; k_probe detects which
// (true-f32 data read as 16-bit words shows exp==0xFF patterns in the low
// halves; true-bf16 finite data never does), k_convert canonicalizes to bf16.

__device__ __forceinline__ float fsigm(float x) {
    return __builtin_amdgcn_rcpf(1.f + __expf(-x));
}
__device__ __forceinline__ float ftanh(float x) {
    x = fminf(10.f, fmaxf(-10.f, x));
    float t = __expf(2.f * x);
    return 1.f - 2.f * __builtin_amdgcn_rcpf(t + 1.f);
}

// ---- dtype probe: flag=1 if input words look like bf16, 0 if f32 ----
__global__ void k_probe(const unsigned short* __restrict__ w, int* __restrict__ flag) {
    __shared__ int cnt;
    if (threadIdx.x == 0) cnt = 0;
    __syncthreads();
    int local = 0;
    for (int i = threadIdx.x; i < 65536; i += 256) {
        unsigned short u = w[i];
        if ((u & 0x7F80) == 0x7F80) local++;   // inf/nan bf16 pattern
    }
    if (local) atomicAdd(&cnt, local);
    __syncthreads();
    if (threadIdx.x == 0) *flag = (cnt == 0) ? 1 : 0;
}

// ---- canonicalize all 21 float tensors into packed bf16 arena ----
struct Ptrs21 { const void* p[21]; };

__global__ void k_convert(Ptrs21 ps, const int* __restrict__ flag, bf16* __restrict__ dst) {
    const int starts[21] = {0,4096,4224,4736,5248,5760,6272,1054848,2103424,2105472,
                            3154048,4202624,4204672,4728960,4729472,5778048,6826624,
                            6828672,6829184,7091328,7353472};
    const int sizes[21]  = {4096,32,512,512,512,512,1048576,1048576,2048,1048576,
                            1048576,2048,524288,512,1048576,1048576,2048,512,
                            262144,262144,512};
    const int total = 7353984;
    bool isbf = (*flag != 0);
    for (int i = blockIdx.x * blockDim.x + threadIdx.x; i < total; i += gridDim.x * blockDim.x) {
        int s = 0;
#pragma unroll
        for (int q = 1; q < 21; ++q) s += (i >= starts[q]) ? 1 : 0;
        int idx = i - starts[s];
        float val = 0.f;
        if (idx < sizes[s])
            val = isbf ? (float)((const bf16*)ps.p[s])[idx] : ((const float*)ps.p[s])[idx];
        dst[i] = (bf16)val;
    }
}

// ---- prep: enc_in embeddings -> bf16 A matrices for fwd/bwd input GEMMs ----
__global__ void k_prep(const bf16* __restrict__ endpoints, const bf16* __restrict__ L,
                       const bf16* __restrict__ ep_w, const bf16* __restrict__ ep_b,
                       const bf16* __restrict__ Lw, const bf16* __restrict__ Lb,
                       bf16* __restrict__ Af, bf16* __restrict__ Ab) {
    const int n = 32 * 128 * 512;
    for (int i = blockIdx.x * blockDim.x + threadIdx.x; i < n; i += gridDim.x * blockDim.x) {
        int k = i & 511; int e = (i >> 9) & 127; int b = i >> 16;
        float val = (float)endpoints[b * 128 + e] * (float)ep_w[k] + (float)ep_b[k]
                  + (float)L[b] * (float)Lw[k] + (float)Lb[k];
        bf16 v16 = (bf16)val;
        Af[(((size_t)e * 32 + b) << 9) + k] = v16;             // row m = e*32+b
        Ab[(((size_t)(127 - e) * 32 + b) << 9) + k] = v16;     // row m = s*32+b, s=127-e
    }
}

// ---- generic MFMA GEMM: C[M][N] = A[M][K] @ W[N][K]^T (+bias), bf16 out ----
__global__ __launch_bounds__(256) void k_gemm(const bf16* __restrict__ A, const bf16* __restrict__ W,
                                              const bf16* __restrict__ bias,
                                              bf16* __restrict__ C, int M, int N, int K) {
    int tid = threadIdx.x; int lane = tid & 63; int wid = tid >> 6;
    int gw = blockIdx.x * 4 + wid;
    int tilesN = N >> 6;
    int tm = gw / tilesN, tn = gw - tm * tilesN;
    const bf16* Ap = A + (size_t)(tm * 16 + (lane & 15)) * K + ((lane >> 4) * 8);
    const bf16* Wp = W + (size_t)(tn * 64 + (lane & 15)) * K + ((lane >> 4) * 8);
    f32x4 acc0 = {0.f, 0.f, 0.f, 0.f}, acc1 = acc0, acc2 = acc0, acc3 = acc0;
    size_t k16 = (size_t)16 * K;
    for (int kk = 0; kk < K; kk += 32) {
        bf16x8 a = *(const bf16x8*)(Ap + kk);
        acc0 = MFMA(a, *(const bf16x8*)(Wp + kk), acc0);
        acc1 = MFMA(a, *(const bf16x8*)(Wp + k16 + kk), acc1);
        acc2 = MFMA(a, *(const bf16x8*)(Wp + 2 * k16 + kk), acc2);
        acc3 = MFMA(a, *(const bf16x8*)(Wp + 3 * k16 + kk), acc3);
    }
    int row0 = tm * 16 + (lane >> 4) * 4;
    int col0 = tn * 64 + (lane & 15);
    f32x4 accs[4] = {acc0, acc1, acc2, acc3};
#pragma unroll
    for (int s = 0; s < 4; ++s) {
        int col = col0 + s * 16;
        float bv = bias ? (float)bias[col] : 0.f;
#pragma unroll
        for (int r = 0; r < 4; ++r) {
            float v = accs[s][r] + bv;
            C[(size_t)(row0 + r) * N + col] = (bf16)v;
        }
    }
}

// ---- bidirectional encoder recurrence (cooperative, 128 blocks x 256 thr) ----
__global__ __launch_bounds__(256) void k_enc(const bf16* __restrict__ Whh_f, const bf16* __restrict__ Whh_b,
                                             const bf16* __restrict__ Xf, const bf16* __restrict__ Xb,
                                             bf16* __restrict__ hstate, bf16* __restrict__ hcat) {
    __shared__ __align__(16) bf16 wp[32][520];
    __shared__ float gl[32][33];
    cg::grid_group grid = cg::this_grid();
    int tid = threadIdx.x; int blk = blockIdx.x;
    int dir = blk >> 6, jblk = blk & 63, j0 = jblk * 8;
    const bf16* Whh = dir ? Whh_b : Whh_f;
    const bf16* X = dir ? Xb : Xf;
    {   // stage 32 weight rows into LDS: wp row c=gate*8+jj <- Whh row gate*512+j0+jj
        int c = tid >> 3; int gate = c >> 3, jj2 = c & 7; int row = gate * 512 + j0 + jj2;
        const bf16* src = Whh + (size_t)row * 512 + (tid & 7) * 64;
        bf16* dst = &wp[c][(tid & 7) * 64];
#pragma unroll
        for (int i2 = 0; i2 < 8; ++i2) ((bf16x8*)dst)[i2] = ((const bf16x8*)src)[i2];
    }
    int b = tid & 31, jj = tid >> 5, jg = j0 + jj;
    size_t sbase = (size_t)dir * 2 * 16384;
    hstate[sbase + b * 512 + jg] = (bf16)0.f;   // h_{-1} = 0 in buf0
    float c_reg = 0.f;
    int lane = tid & 63, wid = tid >> 6, mt = wid & 1, nt = wid >> 1;
    const bf16* wrow = &wp[nt * 16 + (lane & 15)][(lane >> 4) * 8];
    int arow_off = (mt * 16 + (lane & 15)) * 512 + (lane >> 4) * 8;
    grid.sync();
    for (int t = 0; t < 128; ++t) {
        int cur = t & 1, nxt = cur ^ 1;
        const bf16* hp = hstate + sbase + (size_t)cur * 16384 + arow_off;
        f32x4 acc = {0.f, 0.f, 0.f, 0.f};
#pragma unroll
        for (int kk = 0; kk < 512; kk += 32)
            acc = MFMA(*(const bf16x8*)(hp + kk), *(const bf16x8*)(wrow + kk), acc);
        int r0 = mt * 16 + (lane >> 4) * 4, cl = nt * 16 + (lane & 15);
        gl[r0 + 0][cl] = acc[0]; gl[r0 + 1][cl] = acc[1];
        gl[r0 + 2][cl] = acc[2]; gl[r0 + 3][cl] = acc[3];
        __syncthreads();
        const bf16* Xr = X + ((size_t)t * 32 + b) * 2048;
        float gi = gl[b][jj]      + (float)Xr[jg];
        float gf = gl[b][8 + jj]  + (float)Xr[512 + jg];
        float gg = gl[b][16 + jj] + (float)Xr[1024 + jg];
        float go = gl[b][24 + jj] + (float)Xr[1536 + jg];
        c_reg = fsigm(gf) * c_reg + fsigm(gi) * ftanh(gg);
        float h = fsigm(go) * ftanh(c_reg);
        bf16 h16 = (bf16)h;
        hstate[sbase + (size_t)nxt * 16384 + b * 512 + jg] = h16;
        int e = dir ? (127 - t) : t;
        hcat[((size_t)b * 128 + e) * 1024 + dir * 512 + jg] = h16;
        grid.sync();
    }
}

// ---- decoder LSTMCell recurrence (cooperative, 64 blocks x 256 thr) ----
__global__ __launch_bounds__(256) void k_cell(const bf16* __restrict__ dWhh, const bf16* __restrict__ DX,
                                              bf16* __restrict__ hxstate, bf16* __restrict__ hxseq) {
    __shared__ __align__(16) bf16 wp[32][520];
    __shared__ float gl[32][33];
    cg::grid_group grid = cg::this_grid();
    int tid = threadIdx.x; int blk = blockIdx.x;
    int j0 = blk * 8;
    {
        int c = tid >> 3; int gate = c >> 3, jj2 = c & 7; int row = gate * 512 + j0 + jj2;
        const bf16* src = dWhh + (size_t)row * 512 + (tid & 7) * 64;
        bf16* dst = &wp[c][(tid & 7) * 64];
#pragma unroll
        for (int i2 = 0; i2 < 8; ++i2) ((bf16x8*)dst)[i2] = ((const bf16x8*)src)[i2];
    }
    int b = tid & 31, jj = tid >> 5, jg = j0 + jj;
    hxstate[b * 512 + jg] = (bf16)0.f;
    float c_reg = 0.f;
    int lane = tid & 63, wid = tid >> 6, mt = wid & 1, nt = wid >> 1;
    const bf16* wrow = &wp[nt * 16 + (lane & 15)][(lane >> 4) * 8];
    int arow_off = (mt * 16 + (lane & 15)) * 512 + (lane >> 4) * 8;
    grid.sync();
    for (int t = 0; t < 128; ++t) {
        int cur = t & 1, nxt = cur ^ 1;
        const bf16* hp = hxstate + (size_t)cur * 16384 + arow_off;
        f32x4 acc = {0.f, 0.f, 0.f, 0.f};
#pragma unroll
        for (int kk = 0; kk < 512; kk += 32)
            acc = MFMA(*(const bf16x8*)(hp + kk), *(const bf16x8*)(wrow + kk), acc);
        int r0 = mt * 16 + (lane >> 4) * 4, cl = nt * 16 + (lane & 15);
        gl[r0 + 0][cl] = acc[0]; gl[r0 + 1][cl] = acc[1];
        gl[r0 + 2][cl] = acc[2]; gl[r0 + 3][cl] = acc[3];
        __syncthreads();
        const bf16* Xr = DX + ((size_t)t * 32 + b) * 2048;
        float gi = gl[b][jj]      + (float)Xr[jg];
        float gf = gl[b][8 + jj]  + (float)Xr[512 + jg];
        float gg = gl[b][16 + jj] + (float)Xr[1024 + jg];
        float go = gl[b][24 + jj] + (float)Xr[1536 + jg];
        c_reg = fsigm(gf) * c_reg + fsigm(gi) * ftanh(gg);
        float h = fsigm(go) * ftanh(c_reg);
        bf16 h16 = (bf16)h;
        hxstate[(size_t)nxt * 16384 + b * 512 + jg] = h16;
        hxseq[((size_t)t * 32 + b) * 512 + jg] = h16;
        grid.sync();
    }
}

// ---- teacher-forced gather of decoder inputs ----
__global__ void k_gather(const bf16* __restrict__ enc, const int* __restrict__ tseq,
                         const bf16* __restrict__ dec_start, bf16* __restrict__ decin) {
    const int n = 128 * 32 * 512;
    for (int i = blockIdx.x * blockDim.x + threadIdx.x; i < n; i += gridDim.x * blockDim.x) {
        int k = i & 511; int m = i >> 9; int b = m & 31; int t = m >> 5;
        bf16 val;
        if (t == 0) val = dec_start[k];
        else {
            int idx = tseq[b * 128 + (t - 1)];
            if (idx < 128) {
                int ci = idx < 0 ? 0 : idx;
                val = enc[((size_t)b * 128 + ci) * 512 + k];
            } else val = (bf16)0.f;
        }
        decin[i] = val;
    }
}

// ---- batched additive attention + log_softmax; one block per (t,b) row ----
__global__ __launch_bounds__(256) void k_attn(const bf16* __restrict__ enckey, const bf16* __restrict__ dkey,
                                              const bf16* __restrict__ v, const int* __restrict__ flag,
                                              void* __restrict__ outv) {
    __shared__ float dk[512];
    __shared__ float vl[512];
    __shared__ float u[128];
    __shared__ float redm[4];
    __shared__ float reds[4];
    int tid = threadIdx.x;
    int b = blockIdx.x & 31, t = blockIdx.x >> 5;
    int isbf = *flag;
    const bf16* dkr = dkey + ((size_t)t * 32 + b) * 512;
    for (int k = tid; k < 512; k += 256) { dk[k] = (float)dkr[k]; vl[k] = (float)v[k]; }
    __syncthreads();
    int lane = tid & 63, wid = tid >> 6;
    int er = lane >> 3, ch = lane & 7;
    for (int outer = 0; outer < 4; ++outer) {
        int e = outer * 32 + wid * 8 + er;
        const bf16* ek = enckey + ((size_t)b * 128 + e) * 512 + ch * 8;
        float acc = 0.f;
#pragma unroll
        for (int kk = 0; kk < 512; kk += 64) {
            bf16x8 ev = *(const bf16x8*)(ek + kk);
            int kb = kk + ch * 8;
#pragma unroll
            for (int j = 0; j < 8; ++j) {
                float x = (float)ev[j] + dk[kb + j];
                acc = fmaf(ftanh(x), vl[kb + j], acc);
            }
        }
        acc += __shfl_xor(acc, 1); acc += __shfl_xor(acc, 2); acc += __shfl_xor(acc, 4);
        if (ch == 0) u[e] = acc;
    }
    __syncthreads();
    float x = (tid < 128) ? u[tid] : ((tid == 128) ? 0.f : -3.0e38f);
    float wm = x;
#pragma unroll
    for (int o = 32; o >= 1; o >>= 1) wm = fmaxf(wm, __shfl_xor(wm, o));
    if (lane == 0) redm[wid] = wm;
    __syncthreads();
    float M = fmaxf(fmaxf(redm[0], redm[1]), fmaxf(redm[2], redm[3]));
    float ex = (tid <= 128) ? __expf(x - M) : 0.f;
    float ws = ex;
#pragma unroll
    for (int o = 32; o >= 1; o >>= 1) ws += __shfl_xor(ws, o);
    if (lane == 0) reds[wid] = ws;
    __syncthreads();
    float S = reds[0] + reds[1] + reds[2] + reds[3];
    if (tid <= 128) {
        float r = x - M - __logf(S);
        size_t idx = ((size_t)b * 128 + t) * 129 + tid;
        if (isbf) ((bf16*)outv)[idx] = (bf16)r;
        else      ((float*)outv)[idx] = r;
    }
}

extern "C" void kernel_launch(void* const* d_in, const int* in_sizes, int n_in,
                              void* d_out, int out_size, void* d_ws, size_t ws_size,
                              hipStream_t stream) {
    const int* tseq = (const int*)d_in[22];

    char* w = (char*)d_ws;
    auto alloc = [&](size_t bytes) { char* p = w; w += (bytes + 255) & ~(size_t)255; return p; };
    bool roomy = ws_size >= (size_t)92 * 1024 * 1024;

    bf16* canon   = (bf16*)alloc(14707968);   // packed bf16 arena, 7353984 elements
    bf16* Xf      = (bf16*)alloc(16777216);   // [t*32+b][2048]; reused as DX after enc
    bf16* Xb      = (bf16*)alloc(16777216);
    bf16* AfAb    = (bf16*)alloc(8388608);
    bf16* hstate  = (bf16*)alloc(131072);
    bf16* hxstate = (bf16*)alloc(65536);
    int*  flag    = (int*)alloc(256);
    bf16* hcat, *encb, *enckey, *decin, *hxseq, *dkey;
    if (roomy) {
        hcat   = (bf16*)alloc(8388608);
        encb   = (bf16*)alloc(4194304);
        enckey = (bf16*)alloc(4194304);
        decin  = (bf16*)alloc(4194304);
        hxseq  = (bf16*)alloc(4194304);
        dkey   = (bf16*)alloc(4194304);
    } else {                       // overlay fallback (round-2 layout)
        hcat   = AfAb;
        decin  = AfAb;
        encb   = Xb;
        enckey = Xb + 2097152;
        hxseq  = Xb + 2 * 2097152;
        dkey   = Xb + 3 * 2097152;
    }
    bf16* Af = AfAb;
    bf16* Ab = AfAb + 2097152;
    bf16* DX = Xf;

    // canonical tensor offsets (elements)
    bf16* C_endpoints = canon + 0;
    bf16* C_L         = canon + 4096;
    bf16* C_ep_w      = canon + 4224;
    bf16* C_ep_b      = canon + 4736;
    bf16* C_Lw        = canon + 5248;
    bf16* C_Lb        = canon + 5760;
    bf16* C_Wih_f     = canon + 6272;
    bf16* C_Whh_f     = canon + 1054848;
    bf16* C_b_f       = canon + 2103424;
    bf16* C_Wih_b     = canon + 2105472;
    bf16* C_Whh_b     = canon + 3154048;
    bf16* C_b_b       = canon + 4202624;
    bf16* C_proj_w    = canon + 4204672;
    bf16* C_proj_b    = canon + 4728960;
    bf16* C_dWih      = canon + 4729472;
    bf16* C_dWhh      = canon + 5778048;
    bf16* C_db        = canon + 6826624;
    bf16* C_dec_start = canon + 6828672;
    bf16* C_W_enc     = canon + 6829184;
    bf16* C_W_dec     = canon + 7091328;
    bf16* C_v         = canon + 7353472;

    k_probe<<<1, 256, 0, stream>>>((const unsigned short*)d_in[7], flag);
    Ptrs21 ps;
    { // float tensors in setup order, skipping mask(21)/target_seq(22)
        const int order[21] = {0,1,2,3,4,5,6,7,8,9,10,11,12,13,14,15,16,17,18,19,20};
        for (int i = 0; i < 21; ++i) ps.p[i] = d_in[order[i]];
    }
    k_convert<<<2048, 256, 0, stream>>>(ps, flag, canon);

    k_prep<<<2048, 256, 0, stream>>>(C_endpoints, C_L, C_ep_w, C_ep_b, C_Lw, C_Lb, Af, Ab);
    k_gemm<<<2048, 256, 0, stream>>>(Af, C_Wih_f, C_b_f, Xf, 4096, 2048, 512);
    k_gemm<<<2048, 256, 0, stream>>>(Ab, C_Wih_b, C_b_b, Xb, 4096, 2048, 512);
    {
        const bf16* a0 = C_Whh_f; const bf16* a1 = C_Whh_b;
        const bf16* a2 = Xf; const bf16* a3 = Xb;
        bf16* a4 = hstate; bf16* a5 = hcat;
        void* args[] = {&a0, &a1, &a2, &a3, &a4, &a5};
        hipLaunchCooperativeKernel((void*)k_enc, dim3(128), dim3(256), args, 0, stream);
    }
    k_gemm<<<512, 256, 0, stream>>>(hcat, C_proj_w, C_proj_b, encb, 4096, 512, 1024);
    k_gemm<<<512, 256, 0, stream>>>(encb, C_W_enc, nullptr, enckey, 4096, 512, 512);
    k_gather<<<2048, 256, 0, stream>>>(encb, tseq, C_dec_start, decin);
    k_gemm<<<2048, 256, 0, stream>>>(decin, C_dWih, C_db, DX, 4096, 2048, 512);
    {
        const bf16* a0 = C_dWhh; const bf16* a1 = DX;
        bf16* a2 = hxstate; bf16* a3 = hxseq;
        void* args[] = {&a0, &a1, &a2, &a3};
        hipLaunchCooperativeKernel((void*)k_cell, dim3(64), dim3(256), args, 0, stream);
    }
    k_gemm<<<512, 256, 0, stream>>>(hxseq, C_W_dec, nullptr, dkey, 4096, 512, 512);
    k_attn<<<4096, 256, 0, stream>>>(enckey, dkey, C_v, flag, d_out);
}

// Round 7
// 3297.055 us; speedup vs baseline: 1.3898x; 1.3898x over previous
//
#include <hip/hip_runtime.h>
#include <hip/hip_cooperative_groups.h>
#include <hip/hip_bf16.h>

typedef __bf16 bf16;
typedef __bf16 bf16x8 __attribute__((ext_vector_type(8)));
typedef float f32x4 __attribute__((ext_vector_type(4)));

#define MFMA(a, b, c) __builtin_amdgcn_mfma_f32_16x16x32_bf16((a), (b), (c), 0, 0, 0)

// B=32, E=128, T=128, H=512, 4H=2048, E+1=129

__device__ __forceinline__ float fsigm(float x) {
    return __builtin_amdgcn_rcpf(1.f + __expf(-x));
}
__device__ __forceinline__ float ftanh(float x) {
    x = fminf(10.f, fmaxf(-10.f, x));
    float t = __expf(2.f * x);
    return 1.f - 2.f * __builtin_amdgcn_rcpf(t + 1.f);
}

// ---- lightweight grid-subset barrier (monotonic generation counter) ----
// All threads call; tid0 arrives (release) and spins (acquire). Safe because
// cooperative launch guarantees co-residency. Counter zeroed by k_prep.
__device__ __forceinline__ void gbar(int* ctr, int target) {
    __threadfence();          // each thread's stores agent-visible
    __syncthreads();
    if (threadIdx.x == 0) {
        __hip_atomic_fetch_add(ctr, 1, __ATOMIC_RELEASE, __HIP_MEMORY_SCOPE_AGENT);
        while (__hip_atomic_load(ctr, __ATOMIC_ACQUIRE, __HIP_MEMORY_SCOPE_AGENT) < target)
            __builtin_amdgcn_s_sleep(2);
    }
    __syncthreads();
}

// ---- dtype probe: flag=1 if input words look like bf16, 0 if f32 ----
__global__ void k_probe(const unsigned short* __restrict__ w, int* __restrict__ flag) {
    __shared__ int cnt;
    if (threadIdx.x == 0) cnt = 0;
    __syncthreads();
    int local = 0;
    for (int i = threadIdx.x; i < 65536; i += 256) {
        unsigned short u = w[i];
        if ((u & 0x7F80) == 0x7F80) local++;   // inf/nan bf16 pattern
    }
    if (local) atomicAdd(&cnt, local);
    __syncthreads();
    if (threadIdx.x == 0) *flag = (cnt == 0) ? 1 : 0;
}

// ---- canonicalize all 21 float tensors into packed bf16 arena ----
struct Ptrs21 { const void* p[21]; };

__global__ void k_convert(Ptrs21 ps, const int* __restrict__ flag, bf16* __restrict__ dst) {
    const int starts[21] = {0,4096,4224,4736,5248,5760,6272,1054848,2103424,2105472,
                            3154048,4202624,4204672,4728960,4729472,5778048,6826624,
                            6828672,6829184,7091328,7353472};
    const int sizes[21]  = {4096,32,512,512,512,512,1048576,1048576,2048,1048576,
                            1048576,2048,524288,512,1048576,1048576,2048,512,
                            262144,262144,512};
    const int total = 7353984;
    bool isbf = (*flag != 0);
    for (int i = blockIdx.x * blockDim.x + threadIdx.x; i < total; i += gridDim.x * blockDim.x) {
        int s = 0;
#pragma unroll
        for (int q = 1; q < 21; ++q) s += (i >= starts[q]) ? 1 : 0;
        int idx = i - starts[s];
        float val = 0.f;
        if (idx < sizes[s])
            val = isbf ? (float)((const bf16*)ps.p[s])[idx] : ((const float*)ps.p[s])[idx];
        dst[i] = (bf16)val;
    }
}

// ---- prep: embeddings -> A matrices; also zero barrier counters ----
__global__ void k_prep(const bf16* __restrict__ endpoints, const bf16* __restrict__ L,
                       const bf16* __restrict__ ep_w, const bf16* __restrict__ ep_b,
                       const bf16* __restrict__ Lw, const bf16* __restrict__ Lb,
                       bf16* __restrict__ Af, bf16* __restrict__ Ab,
                       int* __restrict__ barctr) {
    if (blockIdx.x == 0 && threadIdx.x < 96) barctr[threadIdx.x] = 0;
    const int n = 32 * 128 * 512;
    for (int i = blockIdx.x * blockDim.x + threadIdx.x; i < n; i += gridDim.x * blockDim.x) {
        int k = i & 511; int e = (i >> 9) & 127; int b = i >> 16;
        float val = (float)endpoints[b * 128 + e] * (float)ep_w[k] + (float)ep_b[k]
                  + (float)L[b] * (float)Lw[k] + (float)Lb[k];
        bf16 v16 = (bf16)val;
        Af[(((size_t)e * 32 + b) << 9) + k] = v16;             // row m = e*32+b
        Ab[(((size_t)(127 - e) * 32 + b) << 9) + k] = v16;     // row m = s*32+b, s=127-e
    }
}

// ---- generic MFMA GEMM: C = A[M][K] @ W[N][K]^T (+bias), bf16 out ----
// mode 0: C[m][n] row-major. mode 1: X^T layout ((m>>5)*N + n)*32 + (m&31)
// (i.e. [t][col][b] for recurrence-coalesced reads).
__global__ __launch_bounds__(256) void k_gemm(const bf16* __restrict__ A, const bf16* __restrict__ W,
                                              const bf16* __restrict__ bias,
                                              bf16* __restrict__ C, int M, int N, int K, int mode) {
    int tid = threadIdx.x; int lane = tid & 63; int wid = tid >> 6;
    int gw = blockIdx.x * 4 + wid;
    int tilesN = N >> 6;
    int tm = gw / tilesN, tn = gw - tm * tilesN;
    const bf16* Ap = A + (size_t)(tm * 16 + (lane & 15)) * K + ((lane >> 4) * 8);
    const bf16* Wp = W + (size_t)(tn * 64 + (lane & 15)) * K + ((lane >> 4) * 8);
    f32x4 acc0 = {0.f, 0.f, 0.f, 0.f}, acc1 = acc0, acc2 = acc0, acc3 = acc0;
    size_t k16 = (size_t)16 * K;
    for (int kk = 0; kk < K; kk += 32) {
        bf16x8 a = *(const bf16x8*)(Ap + kk);
        acc0 = MFMA(a, *(const bf16x8*)(Wp + kk), acc0);
        acc1 = MFMA(a, *(const bf16x8*)(Wp + k16 + kk), acc1);
        acc2 = MFMA(a, *(const bf16x8*)(Wp + 2 * k16 + kk), acc2);
        acc3 = MFMA(a, *(const bf16x8*)(Wp + 3 * k16 + kk), acc3);
    }
    int row0 = tm * 16 + (lane >> 4) * 4;
    int col0 = tn * 64 + (lane & 15);
    f32x4 accs[4] = {acc0, acc1, acc2, acc3};
#pragma unroll
    for (int s = 0; s < 4; ++s) {
        int col = col0 + s * 16;
        float bv = bias ? (float)bias[col] : 0.f;
#pragma unroll
        for (int r = 0; r < 4; ++r) {
            float v = accs[s][r] + bv;
            int row = row0 + r;
            size_t idx = mode ? (((size_t)(row >> 5) * N + col) * 32 + (row & 31))
                              : ((size_t)row * N + col);
            C[idx] = (bf16)v;
        }
    }
}

// ---- bidirectional encoder recurrence: 32 blocks (16/dir) x 512 thr ----
// Block owns 32 hidden units (128 gate rows staged in LDS, 128KB).
// XT layout [t][2048][32]. hstate [dir][buf][b][512]. hcat [b][e][2H].
__global__ __launch_bounds__(512) void k_enc(const bf16* __restrict__ Whh_f, const bf16* __restrict__ Whh_b,
                                             const bf16* __restrict__ XTf, const bf16* __restrict__ XTb,
                                             bf16* __restrict__ hstate, bf16* __restrict__ hcat,
                                             int* __restrict__ barctr) {
    __shared__ __align__(16) bf16 wp[128][520];
    __shared__ float gl[32][129];
    int tid = threadIdx.x, blk = blockIdx.x;
    int dir = blk >> 4, jblk = blk & 15, j0 = jblk * 32;
    const bf16* Whh = dir ? Whh_b : Whh_f;
    const bf16* XT = dir ? XTb : XTf;
    int* ctr = barctr + dir * 32;
    {   // stage 128 gate rows (gate g, unit j0+r -> lds row g*32+r)
        int lr = tid >> 2, q = tid & 3;
        int row = (lr >> 5) * 512 + j0 + (lr & 31);
        const bf16* src = Whh + (size_t)row * 512 + q * 128;
        bf16* dst = &wp[lr][q * 128];
#pragma unroll
        for (int i2 = 0; i2 < 16; ++i2) ((bf16x8*)dst)[i2] = ((const bf16x8*)src)[i2];
    }
    int b = tid & 31, jj = tid >> 5;           // jj 0..15; handles r=jj and r=jj+16
    size_t sbase = (size_t)dir * 2 * 16384;
    hstate[sbase + (size_t)b * 512 + j0 + jj] = (bf16)0.f;
    hstate[sbase + (size_t)b * 512 + j0 + jj + 16] = (bf16)0.f;
    float c0 = 0.f, c1 = 0.f;
    int lane = tid & 63, wid = tid >> 6, mt = wid & 1, nt = wid >> 1;
    const bf16* w0 = &wp[nt * 32 + (lane & 15)][(lane >> 4) * 8];
    const bf16* w1 = &wp[nt * 32 + 16 + (lane & 15)][(lane >> 4) * 8];
    int arow = (mt * 16 + (lane & 15)) * 512 + ((lane >> 4) * 8);
    float xv[8];
    {
        const bf16* xp = XT + (size_t)j0 * 32 + b;
#pragma unroll
        for (int g = 0; g < 4; ++g) {
            xv[g]     = (float)xp[(g * 512 + jj) * 32];
            xv[4 + g] = (float)xp[(g * 512 + jj + 16) * 32];
        }
    }
    gbar(ctr, 16);
    for (int t = 0; t < 128; ++t) {
        int cur = t & 1, nxt = cur ^ 1;
        const bf16* hp = hstate + sbase + (size_t)cur * 16384 + arow;
        f32x4 a0 = {0.f, 0.f, 0.f, 0.f}, a1 = a0;
#pragma unroll
        for (int kk = 0; kk < 16; ++kk) {
            bf16x8 av = *(const bf16x8*)(hp + kk * 32);
            a0 = MFMA(av, *(const bf16x8*)(w0 + kk * 32), a0);
            a1 = MFMA(av, *(const bf16x8*)(w1 + kk * 32), a1);
        }
        int r0 = mt * 16 + (lane >> 4) * 4, cl = nt * 32 + (lane & 15);
#pragma unroll
        for (int r = 0; r < 4; ++r) {
            gl[r0 + r][cl] = a0[r];
            gl[r0 + r][cl + 16] = a1[r];
        }
        __syncthreads();
        float i0 = fsigm(gl[b][jj]      + xv[0]);
        float f0 = fsigm(gl[b][32 + jj] + xv[1]);
        float g0 = ftanh(gl[b][64 + jj] + xv[2]);
        float o0 = fsigm(gl[b][96 + jj] + xv[3]);
        c0 = f0 * c0 + i0 * g0;
        float h0 = o0 * ftanh(c0);
        float i1 = fsigm(gl[b][16 + jj]  + xv[4]);
        float f1 = fsigm(gl[b][48 + jj]  + xv[5]);
        float g1 = ftanh(gl[b][80 + jj]  + xv[6]);
        float o1 = fsigm(gl[b][112 + jj] + xv[7]);
        c1 = f1 * c1 + i1 * g1;
        float h1 = o1 * ftanh(c1);
        bf16 hh0 = (bf16)h0, hh1 = (bf16)h1;
        size_t hb = sbase + (size_t)nxt * 16384 + (size_t)b * 512 + j0;
        hstate[hb + jj] = hh0; hstate[hb + jj + 16] = hh1;
        int e = dir ? (127 - t) : t;
        size_t cb = ((size_t)b * 128 + e) * 1024 + dir * 512 + j0;
        hcat[cb + jj] = hh0; hcat[cb + jj + 16] = hh1;
        if (t < 127) {
            const bf16* xp = XT + ((size_t)(t + 1) * 2048 + j0) * 32 + b;
#pragma unroll
            for (int g = 0; g < 4; ++g) {
                xv[g]     = (float)xp[(g * 512 + jj) * 32];
                xv[4 + g] = (float)xp[(g * 512 + jj + 16) * 32];
            }
        }
        gbar(ctr, 16 * (t + 2));
    }
}

// ---- decoder LSTMCell recurrence: 16 blocks x 512 thr ----
__global__ __launch_bounds__(512) void k_cell(const bf16* __restrict__ dWhh, const bf16* __restrict__ DXT,
                                              bf16* __restrict__ hxstate, bf16* __restrict__ hxseq,
                                              int* __restrict__ barctr) {
    __shared__ __align__(16) bf16 wp[128][520];
    __shared__ float gl[32][129];
    int tid = threadIdx.x, blk = blockIdx.x;
    int j0 = blk * 32;
    int* ctr = barctr + 64;
    {
        int lr = tid >> 2, q = tid & 3;
        int row = (lr >> 5) * 512 + j0 + (lr & 31);
        const bf16* src = dWhh + (size_t)row * 512 + q * 128;
        bf16* dst = &wp[lr][q * 128];
#pragma unroll
        for (int i2 = 0; i2 < 16; ++i2) ((bf16x8*)dst)[i2] = ((const bf16x8*)src)[i2];
    }
    int b = tid & 31, jj = tid >> 5;
    hxstate[(size_t)b * 512 + j0 + jj] = (bf16)0.f;
    hxstate[(size_t)b * 512 + j0 + jj + 16] = (bf16)0.f;
    float c0 = 0.f, c1 = 0.f;
    int lane = tid & 63, wid = tid >> 6, mt = wid & 1, nt = wid >> 1;
    const bf16* w0 = &wp[nt * 32 + (lane & 15)][(lane >> 4) * 8];
    const bf16* w1 = &wp[nt * 32 + 16 + (lane & 15)][(lane >> 4) * 8];
    int arow = (mt * 16 + (lane & 15)) * 512 + ((lane >> 4) * 8);
    float xv[8];
    {
        const bf16* xp = DXT + (size_t)j0 * 32 + b;
#pragma unroll
        for (int g = 0; g < 4; ++g) {
            xv[g]     = (float)xp[(g * 512 + jj) * 32];
            xv[4 + g] = (float)xp[(g * 512 + jj + 16) * 32];
        }
    }
    gbar(ctr, 16);
    for (int t = 0; t < 128; ++t) {
        int cur = t & 1, nxt = cur ^ 1;
        const bf16* hp = hxstate + (size_t)cur * 16384 + arow;
        f32x4 a0 = {0.f, 0.f, 0.f, 0.f}, a1 = a0;
#pragma unroll
        for (int kk = 0; kk < 16; ++kk) {
            bf16x8 av = *(const bf16x8*)(hp + kk * 32);
            a0 = MFMA(av, *(const bf16x8*)(w0 + kk * 32), a0);
            a1 = MFMA(av, *(const bf16x8*)(w1 + kk * 32), a1);
        }
        int r0 = mt * 16 + (lane >> 4) * 4, cl = nt * 32 + (lane & 15);
#pragma unroll
        for (int r = 0; r < 4; ++r) {
            gl[r0 + r][cl] = a0[r];
            gl[r0 + r][cl + 16] = a1[r];
        }
        __syncthreads();
        float i0 = fsigm(gl[b][jj]      + xv[0]);
        float f0 = fsigm(gl[b][32 + jj] + xv[1]);
        float g0 = ftanh(gl[b][64 + jj] + xv[2]);
        float o0 = fsigm(gl[b][96 + jj] + xv[3]);
        c0 = f0 * c0 + i0 * g0;
        float h0 = o0 * ftanh(c0);
        float i1 = fsigm(gl[b][16 + jj]  + xv[4]);
        float f1 = fsigm(gl[b][48 + jj]  + xv[5]);
        float g1 = ftanh(gl[b][80 + jj]  + xv[6]);
        float o1 = fsigm(gl[b][112 + jj] + xv[7]);
        c1 = f1 * c1 + i1 * g1;
        float h1 = o1 * ftanh(c1);
        bf16 hh0 = (bf16)h0, hh1 = (bf16)h1;
        size_t hb = (size_t)nxt * 16384 + (size_t)b * 512 + j0;
        hxstate[hb + jj] = hh0; hxstate[hb + jj + 16] = hh1;
        size_t sb = ((size_t)t * 32 + b) * 512 + j0;
        hxseq[sb + jj] = hh0; hxseq[sb + jj + 16] = hh1;
        if (t < 127) {
            const bf16* xp = DXT + ((size_t)(t + 1) * 2048 + j0) * 32 + b;
#pragma unroll
            for (int g = 0; g < 4; ++g) {
                xv[g]     = (float)xp[(g * 512 + jj) * 32];
                xv[4 + g] = (float)xp[(g * 512 + jj + 16) * 32];
            }
        }
        gbar(ctr, 16 * (t + 2));
    }
}

// ---- teacher-forced gather of decoder inputs ----
__global__ void k_gather(const bf16* __restrict__ enc, const int* __restrict__ tseq,
                         const bf16* __restrict__ dec_start, bf16* __restrict__ decin) {
    const int n = 128 * 32 * 512;
    for (int i = blockIdx.x * blockDim.x + threadIdx.x; i < n; i += gridDim.x * blockDim.x) {
        int k = i & 511; int m = i >> 9; int b = m & 31; int t = m >> 5;
        bf16 val;
        if (t == 0) val = dec_start[k];
        else {
            int idx = tseq[b * 128 + (t - 1)];
            if (idx < 128) {
                int ci = idx < 0 ? 0 : idx;
                val = enc[((size_t)b * 128 + ci) * 512 + k];
            } else val = (bf16)0.f;
        }
        decin[i] = val;
    }
}

// ---- batched additive attention + log_softmax; one block per (t,b) row ----
__global__ __launch_bounds__(256) void k_attn(const bf16* __restrict__ enckey, const bf16* __restrict__ dkey,
                                              const bf16* __restrict__ v, const int* __restrict__ flag,
                                              void* __restrict__ outv) {
    __shared__ float dk[512];
    __shared__ float vl[512];
    __shared__ float u[128];
    __shared__ float redm[4];
    __shared__ float reds[4];
    int tid = threadIdx.x;
    int b = blockIdx.x & 31, t = blockIdx.x >> 5;
    int isbf = *flag;
    const bf16* dkr = dkey + ((size_t)t * 32 + b) * 512;
    for (int k = tid; k < 512; k += 256) { dk[k] = (float)dkr[k]; vl[k] = (float)v[k]; }
    __syncthreads();
    int lane = tid & 63, wid = tid >> 6;
    int er = lane >> 3, ch = lane & 7;
    for (int outer = 0; outer < 4; ++outer) {
        int e = outer * 32 + wid * 8 + er;
        const bf16* ek = enckey + ((size_t)b * 128 + e) * 512 + ch * 8;
        float acc = 0.f;
#pragma unroll
        for (int kk = 0; kk < 512; kk += 64) {
            bf16x8 ev = *(const bf16x8*)(ek + kk);
            int kb = kk + ch * 8;
#pragma unroll
            for (int j = 0; j < 8; ++j) {
                float x = (float)ev[j] + dk[kb + j];
                acc = fmaf(ftanh(x), vl[kb + j], acc);
            }
        }
        acc += __shfl_xor(acc, 1); acc += __shfl_xor(acc, 2); acc += __shfl_xor(acc, 4);
        if (ch == 0) u[e] = acc;
    }
    __syncthreads();
    float x = (tid < 128) ? u[tid] : ((tid == 128) ? 0.f : -3.0e38f);
    float wm = x;
#pragma unroll
    for (int o = 32; o >= 1; o >>= 1) wm = fmaxf(wm, __shfl_xor(wm, o));
    if (lane == 0) redm[wid] = wm;
    __syncthreads();
    float M = fmaxf(fmaxf(redm[0], redm[1]), fmaxf(redm[2], redm[3]));
    float ex = (tid <= 128) ? __expf(x - M) : 0.f;
    float ws = ex;
#pragma unroll
    for (int o = 32; o >= 1; o >>= 1) ws += __shfl_xor(ws, o);
    if (lane == 0) reds[wid] = ws;
    __syncthreads();
    float S = reds[0] + reds[1] + reds[2] + reds[3];
    if (tid <= 128) {
        float r = x - M - __logf(S);
        size_t idx = ((size_t)b * 128 + t) * 129 + tid;
        if (isbf) ((bf16*)outv)[idx] = (bf16)r;
        else      ((float*)outv)[idx] = r;
    }
}

extern "C" void kernel_launch(void* const* d_in, const int* in_sizes, int n_in,
                              void* d_out, int out_size, void* d_ws, size_t ws_size,
                              hipStream_t stream) {
    const int* tseq = (const int*)d_in[22];

    char* w = (char*)d_ws;
    auto alloc = [&](size_t bytes) { char* p = w; w += (bytes + 255) & ~(size_t)255; return p; };
    bool roomy = ws_size >= (size_t)92 * 1024 * 1024;

    bf16* canon   = (bf16*)alloc(14707968);   // packed bf16 arena, 7353984 elements
    bf16* Xf      = (bf16*)alloc(16777216);   // X^T [t][2048][32]; reused as DXT
    bf16* Xb      = (bf16*)alloc(16777216);
    bf16* AfAb    = (bf16*)alloc(8388608);
    bf16* hstate  = (bf16*)alloc(131072);
    bf16* hxstate = (bf16*)alloc(65536);
    int*  flag    = (int*)alloc(256);
    int*  barctr  = (int*)alloc(512);
    bf16* hcat, *encb, *enckey, *decin, *hxseq, *dkey;
    if (roomy) {
        hcat   = (bf16*)alloc(8388608);
        encb   = (bf16*)alloc(4194304);
        enckey = (bf16*)alloc(4194304);
        decin  = (bf16*)alloc(4194304);
        hxseq  = (bf16*)alloc(4194304);
        dkey   = (bf16*)alloc(4194304);
    } else {                       // overlay fallback
        hcat   = AfAb;
        decin  = AfAb;
        encb   = Xb;
        enckey = Xb + 2097152;
        hxseq  = Xb + 2 * 2097152;
        dkey   = Xb + 3 * 2097152;
    }
    bf16* Af = AfAb;
    bf16* Ab = AfAb + 2097152;
    bf16* DXT = Xf;

    // canonical tensor offsets (elements)
    bf16* C_endpoints = canon + 0;
    bf16* C_L         = canon + 4096;
    bf16* C_ep_w      = canon + 4224;
    bf16* C_ep_b      = canon + 4736;
    bf16* C_Lw        = canon + 5248;
    bf16* C_Lb        = canon + 5760;
    bf16* C_Wih_f     = canon + 6272;
    bf16* C_Whh_f     = canon + 1054848;
    bf16* C_b_f       = canon + 2103424;
    bf16* C_Wih_b     = canon + 2105472;
    bf16* C_Whh_b     = canon + 3154048;
    bf16* C_b_b       = canon + 4202624;
    bf16* C_proj_w    = canon + 4204672;
    bf16* C_proj_b    = canon + 4728960;
    bf16* C_dWih      = canon + 4729472;
    bf16* C_dWhh      = canon + 5778048;
    bf16* C_db        = canon + 6826624;
    bf16* C_dec_start = canon + 6828672;
    bf16* C_W_enc     = canon + 6829184;
    bf16* C_W_dec     = canon + 7091328;
    bf16* C_v         = canon + 7353472;

    k_probe<<<1, 256, 0, stream>>>((const unsigned short*)d_in[7], flag);
    Ptrs21 ps;
    for (int i = 0; i < 21; ++i) ps.p[i] = d_in[i];
    k_convert<<<2048, 256, 0, stream>>>(ps, flag, canon);

    k_prep<<<2048, 256, 0, stream>>>(C_endpoints, C_L, C_ep_w, C_ep_b, C_Lw, C_Lb, Af, Ab, barctr);
    k_gemm<<<2048, 256, 0, stream>>>(Af, C_Wih_f, C_b_f, Xf, 4096, 2048, 512, 1);
    k_gemm<<<2048, 256, 0, stream>>>(Ab, C_Wih_b, C_b_b, Xb, 4096, 2048, 512, 1);
    {
        const bf16* a0 = C_Whh_f; const bf16* a1 = C_Whh_b;
        const bf16* a2 = Xf; const bf16* a3 = Xb;
        bf16* a4 = hstate; bf16* a5 = hcat; int* a6 = barctr;
        void* args[] = {&a0, &a1, &a2, &a3, &a4, &a5, &a6};
        hipLaunchCooperativeKernel((void*)k_enc, dim3(32), dim3(512), args, 0, stream);
    }
    k_gemm<<<512, 256, 0, stream>>>(hcat, C_proj_w, C_proj_b, encb, 4096, 512, 1024, 0);
    k_gemm<<<512, 256, 0, stream>>>(encb, C_W_enc, nullptr, enckey, 4096, 512, 512, 0);
    k_gather<<<2048, 256, 0, stream>>>(encb, tseq, C_dec_start, decin);
    k_gemm<<<2048, 256, 0, stream>>>(decin, C_dWih, C_db, DXT, 4096, 2048, 512, 1);
    {
        const bf16* a0 = C_dWhh; const bf16* a1 = DXT;
        bf16* a2 = hxstate; bf16* a3 = hxseq; int* a4 = barctr;
        void* args[] = {&a0, &a1, &a2, &a3, &a4};
        hipLaunchCooperativeKernel((void*)k_cell, dim3(16), dim3(512), args, 0, stream);
    }
    k_gemm<<<512, 256, 0, stream>>>(hxseq, C_W_dec, nullptr, dkey, 4096, 512, 512, 0);
    k_attn<<<4096, 256, 0, stream>>>(enckey, dkey, C_v, flag, d_out);
}

// Round 9
// 2555.537 us; speedup vs baseline: 1.7931x; 1.2902x over previous
//
#include <hip/hip_runtime.h>
#include <hip/hip_cooperative_groups.h>
#include <hip/hip_bf16.h>

typedef __bf16 bf16;
typedef __bf16 bf16x8 __attribute__((ext_vector_type(8)));
typedef float f32x4 __attribute__((ext_vector_type(4)));

#define MFMA(a, b, c) __builtin_amdgcn_mfma_f32_16x16x32_bf16((a), (b), (c), 0, 0, 0)

// B=32, E=128, T=128, H=512, 4H=2048, E+1=129

__device__ __forceinline__ float fsigm(float x) {
    return __builtin_amdgcn_rcpf(1.f + __expf(-x));
}
__device__ __forceinline__ float ftanh(float x) {
    x = fminf(10.f, fmaxf(-10.f, x));
    float t = __expf(2.f * x);
    return 1.f - 2.f * __builtin_amdgcn_rcpf(t + 1.f);
}

// ---- lightweight grid-subset barrier (monotonic generation counter) ----
// __syncthreads drains vmcnt (L1 write-through => all block stores are in L2);
// the leader's RELEASE atomic emits the single L2 writeback that publishes
// them agent-wide; ACQUIRE load + trailing __syncthreads handles invalidation.
// (Round-7 version had ALL waves execute __threadfence = 8 redundant L2
// writebacks per step; that was the ~6us/step hidden constant hypothesis.)
__device__ __forceinline__ void gbar(int* ctr, int target) {
    __syncthreads();
    if (threadIdx.x == 0) {
        __hip_atomic_fetch_add(ctr, 1, __ATOMIC_RELEASE, __HIP_MEMORY_SCOPE_AGENT);
        while (__hip_atomic_load(ctr, __ATOMIC_ACQUIRE, __HIP_MEMORY_SCOPE_AGENT) < target)
            __builtin_amdgcn_s_sleep(2);
    }
    __syncthreads();
}

// ---- dtype probe: flag=1 if input words look like bf16, 0 if f32 ----
__global__ void k_probe(const unsigned short* __restrict__ w, int* __restrict__ flag) {
    __shared__ int cnt;
    if (threadIdx.x == 0) cnt = 0;
    __syncthreads();
    int local = 0;
    for (int i = threadIdx.x; i < 65536; i += 256) {
        unsigned short u = w[i];
        if ((u & 0x7F80) == 0x7F80) local++;   // inf/nan bf16 pattern
    }
    if (local) atomicAdd(&cnt, local);
    __syncthreads();
    if (threadIdx.x == 0) *flag = (cnt == 0) ? 1 : 0;
}

// ---- canonicalize all 21 float tensors into packed bf16 arena ----
struct Ptrs21 { const void* p[21]; };

__global__ void k_convert(Ptrs21 ps, const int* __restrict__ flag, bf16* __restrict__ dst) {
    const int starts[21] = {0,4096,4224,4736,5248,5760,6272,1054848,2103424,2105472,
                            3154048,4202624,4204672,4728960,4729472,5778048,6826624,
                            6828672,6829184,7091328,7353472};
    const int sizes[21]  = {4096,32,512,512,512,512,1048576,1048576,2048,1048576,
                            1048576,2048,524288,512,1048576,1048576,2048,512,
                            262144,262144,512};
    const int total = 7353984;
    bool isbf = (*flag != 0);
    for (int i = blockIdx.x * blockDim.x + threadIdx.x; i < total; i += gridDim.x * blockDim.x) {
        int s = 0;
#pragma unroll
        for (int q = 1; q < 21; ++q) s += (i >= starts[q]) ? 1 : 0;
        int idx = i - starts[s];
        float val = 0.f;
        if (idx < sizes[s])
            val = isbf ? (float)((const bf16*)ps.p[s])[idx] : ((const float*)ps.p[s])[idx];
        dst[i] = (bf16)val;
    }
}

// ---- prep: embeddings -> A matrices; also zero barrier counters ----
__global__ void k_prep(const bf16* __restrict__ endpoints, const bf16* __restrict__ L,
                       const bf16* __restrict__ ep_w, const bf16* __restrict__ ep_b,
                       const bf16* __restrict__ Lw, const bf16* __restrict__ Lb,
                       bf16* __restrict__ Af, bf16* __restrict__ Ab,
                       int* __restrict__ barctr) {
    if (blockIdx.x == 0 && threadIdx.x < 96) barctr[threadIdx.x] = 0;
    const int n = 32 * 128 * 512;
    for (int i = blockIdx.x * blockDim.x + threadIdx.x; i < n; i += gridDim.x * blockDim.x) {
        int k = i & 511; int e = (i >> 9) & 127; int b = i >> 16;
        float val = (float)endpoints[b * 128 + e] * (float)ep_w[k] + (float)ep_b[k]
                  + (float)L[b] * (float)Lw[k] + (float)Lb[k];
        bf16 v16 = (bf16)val;
        Af[(((size_t)e * 32 + b) << 9) + k] = v16;             // row m = e*32+b
        Ab[(((size_t)(127 - e) * 32 + b) << 9) + k] = v16;     // row m = s*32+b, s=127-e
    }
}

// ---- generic MFMA GEMM: C = A[M][K] @ W[N][K]^T (+bias), bf16 out ----
// mode 0: C[m][n] row-major. mode 1: X^T layout ((m>>5)*N + n)*32 + (m&31)
// (i.e. [t][col][b] for recurrence-coalesced reads).
__global__ __launch_bounds__(256) void k_gemm(const bf16* __restrict__ A, const bf16* __restrict__ W,
                                              const bf16* __restrict__ bias,
                                              bf16* __restrict__ C, int M, int N, int K, int mode) {
    int tid = threadIdx.x; int lane = tid & 63; int wid = tid >> 6;
    int gw = blockIdx.x * 4 + wid;
    int tilesN = N >> 6;
    int tm = gw / tilesN, tn = gw - tm * tilesN;
    const bf16* Ap = A + (size_t)(tm * 16 + (lane & 15)) * K + ((lane >> 4) * 8);
    const bf16* Wp = W + (size_t)(tn * 64 + (lane & 15)) * K + ((lane >> 4) * 8);
    f32x4 acc0 = {0.f, 0.f, 0.f, 0.f}, acc1 = acc0, acc2 = acc0, acc3 = acc0;
    size_t k16 = (size_t)16 * K;
    for (int kk = 0; kk < K; kk += 32) {
        bf16x8 a = *(const bf16x8*)(Ap + kk);
        acc0 = MFMA(a, *(const bf16x8*)(Wp + kk), acc0);
        acc1 = MFMA(a, *(const bf16x8*)(Wp + k16 + kk), acc1);
        acc2 = MFMA(a, *(const bf16x8*)(Wp + 2 * k16 + kk), acc2);
        acc3 = MFMA(a, *(const bf16x8*)(Wp + 3 * k16 + kk), acc3);
    }
    int row0 = tm * 16 + (lane >> 4) * 4;
    int col0 = tn * 64 + (lane & 15);
    f32x4 accs[4] = {acc0, acc1, acc2, acc3};
#pragma unroll
    for (int s = 0; s < 4; ++s) {
        int col = col0 + s * 16;
        float bv = bias ? (float)bias[col] : 0.f;
#pragma unroll
        for (int r = 0; r < 4; ++r) {
            float v = accs[s][r] + bv;
            int row = row0 + r;
            size_t idx = mode ? (((size_t)(row >> 5) * N + col) * 32 + (row & 31))
                              : ((size_t)row * N + col);
            C[idx] = (bf16)v;
        }
    }
}

// ---- bidirectional encoder recurrence: 32 blocks (16/dir) x 512 thr ----
// Block owns 32 hidden units (128 gate rows staged in LDS, 128KB).
// XT layout [t][2048][32]. hstate [dir][buf][b][512]. hcat [b][e][2H].
__global__ __launch_bounds__(512) void k_enc(const bf16* __restrict__ Whh_f, const bf16* __restrict__ Whh_b,
                                             const bf16* __restrict__ XTf, const bf16* __restrict__ XTb,
                                             bf16* __restrict__ hstate, bf16* __restrict__ hcat,
                                             int* __restrict__ barctr) {
    __shared__ __align__(16) bf16 wp[128][520];
    __shared__ float gl[32][129];
    int tid = threadIdx.x, blk = blockIdx.x;
    int dir = blk >> 4, jblk = blk & 15, j0 = jblk * 32;
    const bf16* Whh = dir ? Whh_b : Whh_f;
    const bf16* XT = dir ? XTb : XTf;
    int* ctr = barctr + dir * 32;
    {   // stage 128 gate rows (gate g, unit j0+r -> lds row g*32+r)
        int lr = tid >> 2, q = tid & 3;
        int row = (lr >> 5) * 512 + j0 + (lr & 31);
        const bf16* src = Whh + (size_t)row * 512 + q * 128;
        bf16* dst = &wp[lr][q * 128];
#pragma unroll
        for (int i2 = 0; i2 < 16; ++i2) ((bf16x8*)dst)[i2] = ((const bf16x8*)src)[i2];
    }
    int b = tid & 31, jj = tid >> 5;           // jj 0..15; handles r=jj and r=jj+16
    size_t sbase = (size_t)dir * 2 * 16384;
    hstate[sbase + (size_t)b * 512 + j0 + jj] = (bf16)0.f;
    hstate[sbase + (size_t)b * 512 + j0 + jj + 16] = (bf16)0.f;
    float c0 = 0.f, c1 = 0.f;
    int lane = tid & 63, wid = tid >> 6, mt = wid & 1, nt = wid >> 1;
    const bf16* w0 = &wp[nt * 32 + (lane & 15)][(lane >> 4) * 8];
    const bf16* w1 = &wp[nt * 32 + 16 + (lane & 15)][(lane >> 4) * 8];
    int arow = (mt * 16 + (lane & 15)) * 512 + ((lane >> 4) * 8);
    float xv[8];
    {
        const bf16* xp = XT + (size_t)j0 * 32 + b;
#pragma unroll
        for (int g = 0; g < 4; ++g) {
            xv[g]     = (float)__builtin_nontemporal_load(&xp[(g * 512 + jj) * 32]);
            xv[4 + g] = (float)__builtin_nontemporal_load(&xp[(g * 512 + jj + 16) * 32]);
        }
    }
    gbar(ctr, 16);
    for (int t = 0; t < 128; ++t) {
        int cur = t & 1, nxt = cur ^ 1;
        const bf16* hp = hstate + sbase + (size_t)cur * 16384 + arow;
        f32x4 a0 = {0.f, 0.f, 0.f, 0.f}, a1 = a0;
#pragma unroll
        for (int kk = 0; kk < 16; ++kk) {
            bf16x8 av = *(const bf16x8*)(hp + kk * 32);
            a0 = MFMA(av, *(const bf16x8*)(w0 + kk * 32), a0);
            a1 = MFMA(av, *(const bf16x8*)(w1 + kk * 32), a1);
        }
        int r0 = mt * 16 + (lane >> 4) * 4, cl = nt * 32 + (lane & 15);
#pragma unroll
        for (int r = 0; r < 4; ++r) {
            gl[r0 + r][cl] = a0[r];
            gl[r0 + r][cl + 16] = a1[r];
        }
        __syncthreads();
        float i0 = fsigm(gl[b][jj]      + xv[0]);
        float f0 = fsigm(gl[b][32 + jj] + xv[1]);
        float g0 = ftanh(gl[b][64 + jj] + xv[2]);
        float o0 = fsigm(gl[b][96 + jj] + xv[3]);
        c0 = f0 * c0 + i0 * g0;
        float h0 = o0 * ftanh(c0);
        float i1 = fsigm(gl[b][16 + jj]  + xv[4]);
        float f1 = fsigm(gl[b][48 + jj]  + xv[5]);
        float g1 = ftanh(gl[b][80 + jj]  + xv[6]);
        float o1 = fsigm(gl[b][112 + jj] + xv[7]);
        c1 = f1 * c1 + i1 * g1;
        float h1 = o1 * ftanh(c1);
        bf16 hh0 = (bf16)h0, hh1 = (bf16)h1;
        size_t hb = sbase + (size_t)nxt * 16384 + (size_t)b * 512 + j0;
        hstate[hb + jj] = hh0; hstate[hb + jj + 16] = hh1;
        int e = dir ? (127 - t) : t;
        size_t cb = ((size_t)b * 128 + e) * 1024 + dir * 512 + j0;
        __builtin_nontemporal_store(hh0, &hcat[cb + jj]);
        __builtin_nontemporal_store(hh1, &hcat[cb + jj + 16]);
        if (t < 127) {
            const bf16* xp = XT + ((size_t)(t + 1) * 2048 + j0) * 32 + b;
#pragma unroll
            for (int g = 0; g < 4; ++g) {
                xv[g]     = (float)__builtin_nontemporal_load(&xp[(g * 512 + jj) * 32]);
                xv[4 + g] = (float)__builtin_nontemporal_load(&xp[(g * 512 + jj + 16) * 32]);
            }
        }
        gbar(ctr, 16 * (t + 2));
    }
}

// ---- decoder LSTMCell recurrence: 16 blocks x 512 thr ----
__global__ __launch_bounds__(512) void k_cell(const bf16* __restrict__ dWhh, const bf16* __restrict__ DXT,
                                              bf16* __restrict__ hxstate, bf16* __restrict__ hxseq,
                                              int* __restrict__ barctr) {
    __shared__ __align__(16) bf16 wp[128][520];
    __shared__ float gl[32][129];
    int tid = threadIdx.x, blk = blockIdx.x;
    int j0 = blk * 32;
    int* ctr = barctr + 64;
    {
        int lr = tid >> 2, q = tid & 3;
        int row = (lr >> 5) * 512 + j0 + (lr & 31);
        const bf16* src = dWhh + (size_t)row * 512 + q * 128;
        bf16* dst = &wp[lr][q * 128];
#pragma unroll
        for (int i2 = 0; i2 < 16; ++i2) ((bf16x8*)dst)[i2] = ((const bf16x8*)src)[i2];
    }
    int b = tid & 31, jj = tid >> 5;
    hxstate[(size_t)b * 512 + j0 + jj] = (bf16)0.f;
    hxstate[(size_t)b * 512 + j0 + jj + 16] = (bf16)0.f;
    float c0 = 0.f, c1 = 0.f;
    int lane = tid & 63, wid = tid >> 6, mt = wid & 1, nt = wid >> 1;
    const bf16* w0 = &wp[nt * 32 + (lane & 15)][(lane >> 4) * 8];
    const bf16* w1 = &wp[nt * 32 + 16 + (lane & 15)][(lane >> 4) * 8];
    int arow = (mt * 16 + (lane & 15)) * 512 + ((lane >> 4) * 8);
    float xv[8];
    {
        const bf16* xp = DXT + (size_t)j0 * 32 + b;
#pragma unroll
        for (int g = 0; g < 4; ++g) {
            xv[g]     = (float)__builtin_nontemporal_load(&xp[(g * 512 + jj) * 32]);
            xv[4 + g] = (float)__builtin_nontemporal_load(&xp[(g * 512 + jj + 16) * 32]);
        }
    }
    gbar(ctr, 16);
    for (int t = 0; t < 128; ++t) {
        int cur = t & 1, nxt = cur ^ 1;
        const bf16* hp = hxstate + (size_t)cur * 16384 + arow;
        f32x4 a0 = {0.f, 0.f, 0.f, 0.f}, a1 = a0;
#pragma unroll
        for (int kk = 0; kk < 16; ++kk) {
            bf16x8 av = *(const bf16x8*)(hp + kk * 32);
            a0 = MFMA(av, *(const bf16x8*)(w0 + kk * 32), a0);
            a1 = MFMA(av, *(const bf16x8*)(w1 + kk * 32), a1);
        }
        int r0 = mt * 16 + (lane >> 4) * 4, cl = nt * 32 + (lane & 15);
#pragma unroll
        for (int r = 0; r < 4; ++r) {
            gl[r0 + r][cl] = a0[r];
            gl[r0 + r][cl + 16] = a1[r];
        }
        __syncthreads();
        float i0 = fsigm(gl[b][jj]      + xv[0]);
        float f0 = fsigm(gl[b][32 + jj] + xv[1]);
        float g0 = ftanh(gl[b][64 + jj] + xv[2]);
        float o0 = fsigm(gl[b][96 + jj] + xv[3]);
        c0 = f0 * c0 + i0 * g0;
        float h0 = o0 * ftanh(c0);
        float i1 = fsigm(gl[b][16 + jj]  + xv[4]);
        float f1 = fsigm(gl[b][48 + jj]  + xv[5]);
        float g1 = ftanh(gl[b][80 + jj]  + xv[6]);
        float o1 = fsigm(gl[b][112 + jj] + xv[7]);
        c1 = f1 * c1 + i1 * g1;
        float h1 = o1 * ftanh(c1);
        bf16 hh0 = (bf16)h0, hh1 = (bf16)h1;
        size_t hb = (size_t)nxt * 16384 + (size_t)b * 512 + j0;
        hxstate[hb + jj] = hh0; hxstate[hb + jj + 16] = hh1;
        size_t sb = ((size_t)t * 32 + b) * 512 + j0;
        __builtin_nontemporal_store(hh0, &hxseq[sb + jj]);
        __builtin_nontemporal_store(hh1, &hxseq[sb + jj + 16]);
        if (t < 127) {
            const bf16* xp = DXT + ((size_t)(t + 1) * 2048 + j0) * 32 + b;
#pragma unroll
            for (int g = 0; g < 4; ++g) {
                xv[g]     = (float)__builtin_nontemporal_load(&xp[(g * 512 + jj) * 32]);
                xv[4 + g] = (float)__builtin_nontemporal_load(&xp[(g * 512 + jj + 16) * 32]);
            }
        }
        gbar(ctr, 16 * (t + 2));
    }
}

// ---- teacher-forced gather of decoder inputs ----
__global__ void k_gather(const bf16* __restrict__ enc, const int* __restrict__ tseq,
                         const bf16* __restrict__ dec_start, bf16* __restrict__ decin) {
    const int n = 128 * 32 * 512;
    for (int i = blockIdx.x * blockDim.x + threadIdx.x; i < n; i += gridDim.x * blockDim.x) {
        int k = i & 511; int m = i >> 9; int b = m & 31; int t = m >> 5;
        bf16 val;
        if (t == 0) val = dec_start[k];
        else {
            int idx = tseq[b * 128 + (t - 1)];
            if (idx < 128) {
                int ci = idx < 0 ? 0 : idx;
                val = enc[((size_t)b * 128 + ci) * 512 + k];
            } else val = (bf16)0.f;
        }
        decin[i] = val;
    }
}

// ---- batched additive attention + log_softmax; one block per (t,b) row ----
__global__ __launch_bounds__(256) void k_attn(const bf16* __restrict__ enckey, const bf16* __restrict__ dkey,
                                              const bf16* __restrict__ v, const int* __restrict__ flag,
                                              void* __restrict__ outv) {
    __shared__ float dk[512];
    __shared__ float vl[512];
    __shared__ float u[128];
    __shared__ float redm[4];
    __shared__ float reds[4];
    int tid = threadIdx.x;
    int b = blockIdx.x & 31, t = blockIdx.x >> 5;
    int isbf = *flag;
    const bf16* dkr = dkey + ((size_t)t * 32 + b) * 512;
    for (int k = tid; k < 512; k += 256) { dk[k] = (float)dkr[k]; vl[k] = (float)v[k]; }
    __syncthreads();
    int lane = tid & 63, wid = tid >> 6;
    int er = lane >> 3, ch = lane & 7;
    for (int outer = 0; outer < 4; ++outer) {
        int e = outer * 32 + wid * 8 + er;
        const bf16* ek = enckey + ((size_t)b * 128 + e) * 512 + ch * 8;
        float acc = 0.f;
#pragma unroll
        for (int kk = 0; kk < 512; kk += 64) {
            bf16x8 ev = *(const bf16x8*)(ek + kk);
            int kb = kk + ch * 8;
#pragma unroll
            for (int j = 0; j < 8; ++j) {
                float x = (float)ev[j] + dk[kb + j];
                acc = fmaf(ftanh(x), vl[kb + j], acc);
            }
        }
        acc += __shfl_xor(acc, 1); acc += __shfl_xor(acc, 2); acc += __shfl_xor(acc, 4);
        if (ch == 0) u[e] = acc;
    }
    __syncthreads();
    float x = (tid < 128) ? u[tid] : ((tid == 128) ? 0.f : -3.0e38f);
    float wm = x;
#pragma unroll
    for (int o = 32; o >= 1; o >>= 1) wm = fmaxf(wm, __shfl_xor(wm, o));
    if (lane == 0) redm[wid] = wm;
    __syncthreads();
    float M = fmaxf(fmaxf(redm[0], redm[1]), fmaxf(redm[2], redm[3]));
    float ex = (tid <= 128) ? __expf(x - M) : 0.f;
    float ws = ex;
#pragma unroll
    for (int o = 32; o >= 1; o >>= 1) ws += __shfl_xor(ws, o);
    if (lane == 0) reds[wid] = ws;
    __syncthreads();
    float S = reds[0] + reds[1] + reds[2] + reds[3];
    if (tid <= 128) {
        float r = x - M - __logf(S);
        size_t idx = ((size_t)b * 128 + t) * 129 + tid;
        if (isbf) ((bf16*)outv)[idx] = (bf16)r;
        else      ((float*)outv)[idx] = r;
    }
}

extern "C" void kernel_launch(void* const* d_in, const int* in_sizes, int n_in,
                              void* d_out, int out_size, void* d_ws, size_t ws_size,
                              hipStream_t stream) {
    const int* tseq = (const int*)d_in[22];

    char* w = (char*)d_ws;
    auto alloc = [&](size_t bytes) { char* p = w; w += (bytes + 255) & ~(size_t)255; return p; };
    bool roomy = ws_size >= (size_t)92 * 1024 * 1024;

    bf16* canon   = (bf16*)alloc(14707968);   // packed bf16 arena, 7353984 elements
    bf16* Xf      = (bf16*)alloc(16777216);   // X^T [t][2048][32]; reused as DXT
    bf16* Xb      = (bf16*)alloc(16777216);
    bf16* AfAb    = (bf16*)alloc(8388608);
    bf16* hstate  = (bf16*)alloc(131072);
    bf16* hxstate = (bf16*)alloc(65536);
    int*  flag    = (int*)alloc(256);
    int*  barctr  = (int*)alloc(512);
    bf16* hcat, *encb, *enckey, *decin, *hxseq, *dkey;
    if (roomy) {
        hcat   = (bf16*)alloc(8388608);
        encb   = (bf16*)alloc(4194304);
        enckey = (bf16*)alloc(4194304);
        decin  = (bf16*)alloc(4194304);
        hxseq  = (bf16*)alloc(4194304);
        dkey   = (bf16*)alloc(4194304);
    } else {                       // overlay fallback
        hcat   = AfAb;
        decin  = AfAb;
        encb   = Xb;
        enckey = Xb + 2097152;
        hxseq  = Xb + 2 * 2097152;
        dkey   = Xb + 3 * 2097152;
    }
    bf16* Af = AfAb;
    bf16* Ab = AfAb + 2097152;
    bf16* DXT = Xf;

    // canonical tensor offsets (elements)
    bf16* C_endpoints = canon + 0;
    bf16* C_L         = canon + 4096;
    bf16* C_ep_w      = canon + 4224;
    bf16* C_ep_b      = canon + 4736;
    bf16* C_Lw        = canon + 5248;
    bf16* C_Lb        = canon + 5760;
    bf16* C_Wih_f     = canon + 6272;
    bf16* C_Whh_f     = canon + 1054848;
    bf16* C_b_f       = canon + 2103424;
    bf16* C_Wih_b     = canon + 2105472;
    bf16* C_Whh_b     = canon + 3154048;
    bf16* C_b_b       = canon + 4202624;
    bf16* C_proj_w    = canon + 4204672;
    bf16* C_proj_b    = canon + 4728960;
    bf16* C_dWih      = canon + 4729472;
    bf16* C_dWhh      = canon + 5778048;
    bf16* C_db        = canon + 6826624;
    bf16* C_dec_start = canon + 6828672;
    bf16* C_W_enc     = canon + 6829184;
    bf16* C_W_dec     = canon + 7091328;
    bf16* C_v         = canon + 7353472;

    k_probe<<<1, 256, 0, stream>>>((const unsigned short*)d_in[7], flag);
    Ptrs21 ps;
    for (int i = 0; i < 21; ++i) ps.p[i] = d_in[i];
    k_convert<<<2048, 256, 0, stream>>>(ps, flag, canon);

    k_prep<<<2048, 256, 0, stream>>>(C_endpoints, C_L, C_ep_w, C_ep_b, C_Lw, C_Lb, Af, Ab, barctr);
    k_gemm<<<2048, 256, 0, stream>>>(Af, C_Wih_f, C_b_f, Xf, 4096, 2048, 512, 1);
    k_gemm<<<2048, 256, 0, stream>>>(Ab, C_Wih_b, C_b_b, Xb, 4096, 2048, 512, 1);
    {
        const bf16* a0 = C_Whh_f; const bf16* a1 = C_Whh_b;
        const bf16* a2 = Xf; const bf16* a3 = Xb;
        bf16* a4 = hstate; bf16* a5 = hcat; int* a6 = barctr;
        void* args[] = {&a0, &a1, &a2, &a3, &a4, &a5, &a6};
        hipLaunchCooperativeKernel((void*)k_enc, dim3(32), dim3(512), args, 0, stream);
    }
    k_gemm<<<512, 256, 0, stream>>>(hcat, C_proj_w, C_proj_b, encb, 4096, 512, 1024, 0);
    k_gemm<<<512, 256, 0, stream>>>(encb, C_W_enc, nullptr, enckey, 4096, 512, 512, 0);
    k_gather<<<2048, 256, 0, stream>>>(encb, tseq, C_dec_start, decin);
    k_gemm<<<2048, 256, 0, stream>>>(decin, C_dWih, C_db, DXT, 4096, 2048, 512, 1);
    {
        const bf16* a0 = C_dWhh; const bf16* a1 = DXT;
        bf16* a2 = hxstate; bf16* a3 = hxseq; int* a4 = barctr;
        void* args[] = {&a0, &a1, &a2, &a3, &a4};
        hipLaunchCooperativeKernel((void*)k_cell, dim3(16), dim3(512), args, 0, stream);
    }
    k_gemm<<<512, 256, 0, stream>>>(hxseq, C_W_dec, nullptr, dkey, 4096, 512, 512, 0);
    k_attn<<<4096, 256, 0, stream>>>(enckey, dkey, C_v, flag, d_out);
}